// Round 4
// baseline (699.094 us; speedup 1.0000x reference)
//
#include <hip/hip_runtime.h>

#define BQ   16
#define HH   96
#define WWD  96
#define CIN  64
#define COUT 128
#define KK   3

typedef float f32x4 __attribute__((ext_vector_type(4)));

// Fully fused: out[(tap,b,i), j, o] = rowsum(b, i+x-1)[j+y-1] * wsum[tap][o]
// One block per (tap,b,i). Each block:
//   1) computes wsum[tap][*] from W (64 KB, L2-resident — re-read by all blocks of the tap)
//   2) computes the channel-sum of its single input row (24.6 KB, L3-resident)
//   3) streams a contiguous 48 KB output strip with non-temporal float4 stores.
// HBM write stream (679.5 MB total) is the only real traffic.
__global__ __launch_bounds__(256) void k_fused(const float* __restrict__ in,
                                               const float* __restrict__ W,
                                               float* __restrict__ out) {
    int bid = blockIdx.x;                  // (tap*BQ + b)*HH + i
    int tap = bid / (BQ * HH);
    int rem = bid - tap * (BQ * HH);
    int b   = rem / HH;
    int i   = rem - b * HH;
    int x   = tap / 3, y = tap - x * 3;

    int t = threadIdx.x;

    __shared__ float ws[COUT];
    __shared__ float srow[WWD];
    __shared__ float red[256];

    // ---- wsum[tap][o] ----
    {
        int o    = t & (COUT - 1);         // 0..127
        int half = t >> 7;                 // 0 or 1
        const float* base = W + (size_t)tap * COUT * COUT + (size_t)(half * 64) * COUT + o;
        float acc = 0.f;
#pragma unroll 8
        for (int c = 0; c < 64; ++c) acc += base[(size_t)c * COUT];
        red[t] = acc;
        __syncthreads();
        if (t < COUT) ws[t] = red[t] + red[t + COUT];
    }

    // ---- channel-sum of input row ii ----
    int ii = i + x - 1;
    bool rowok = (unsigned)ii < (unsigned)HH;
    if (rowok) {
        const float* rbase = in + ((size_t)b * HH + ii) * (WWD * CIN);
        int g = t & 15;                    // lane within 16-lane pixel group
#pragma unroll
        for (int it = 0; it < (WWD * 16) / 256; ++it) {   // 6 iters
            int pixel = (it * 256 + t) >> 4;              // 0..95
            f32x4 v = *((const f32x4*)(rbase + (size_t)pixel * CIN) + g);
            float acc = (v.x + v.y) + (v.z + v.w);
            acc += __shfl_xor(acc, 1);
            acc += __shfl_xor(acc, 2);
            acc += __shfl_xor(acc, 4);
            acc += __shfl_xor(acc, 8);
            if (g == 0) srow[pixel] = acc;
        }
    }
    __syncthreads();                       // covers ws and srow

    // ---- output strip: 96 j x 128 o, contiguous 48 KB ----
    int ob = (t & 31) * 4;                 // output-channel base
    int jt = t >> 5;                       // j sub-index 0..7
    f32x4 w = *(const f32x4*)(ws + ob);
    float* orow = out + (size_t)bid * (WWD * COUT) + ob;
#pragma unroll
    for (int it = 0; it < WWD / 8; ++it) {
        int j  = it * 8 + jt;
        int jj = j + y - 1;
        float sv = (rowok && (unsigned)jj < (unsigned)WWD) ? srow[jj] : 0.f;
        f32x4 v = { sv * w.x, sv * w.y, sv * w.z, sv * w.w };
        __builtin_nontemporal_store(v, (f32x4*)(orow + (size_t)j * COUT));
    }
}

extern "C" void kernel_launch(void* const* d_in, const int* in_sizes, int n_in,
                              void* d_out, int out_size, void* d_ws, size_t ws_size,
                              hipStream_t stream) {
    const float* in = (const float*)d_in[0];   // [16,96,96,64]
    const float* W  = (const float*)d_in[1];   // [3,3,128,128]
    float* out = (float*)d_out;                // [3,3,16,96,96,128]

    k_fused<<<KK * KK * BQ * HH, 256, 0, stream>>>(in, W, out);
}

// Round 7
// 688.121 us; speedup vs baseline: 1.0159x; 1.0159x over previous
//
#include <hip/hip_runtime.h>

#define BQ   16
#define HH   96
#define WWD  96
#define CIN  64
#define COUT 128
#define KK   3
#define NPIX (BQ * HH * WWD)   // 147456

typedef float f32x4 __attribute__((ext_vector_type(4)));

// Fused prep kernel.
// Blocks 0..8   : wsum[tap][o] = sum_c W[tap][c][o]
// Blocks 9..584 : s[p] = sum_c inputs[p*64+c], 256 pixels per block,
//                 16 lanes per pixel (fully coalesced 1 KB/wave reads).
__global__ __launch_bounds__(256) void k_prep(const float* __restrict__ in,
                                              const float* __restrict__ W,
                                              float* __restrict__ s,
                                              float* __restrict__ wsum) {
    int t = threadIdx.x;
    if (blockIdx.x < KK * KK) {
        // --- wsum for one tap ---
        int tap = blockIdx.x;
        int o    = t & (COUT - 1);       // 0..127
        int half = t >> 7;               // 0 or 1
        const float* base = W + (size_t)tap * COUT * COUT + (size_t)half * 64 * COUT + o;
        float acc = 0.f;
#pragma unroll 8
        for (int c = 0; c < 64; ++c) acc += base[(size_t)c * COUT];
        __shared__ float red[256];
        red[t] = acc;
        __syncthreads();
        if (t < COUT) wsum[tap * COUT + t] = red[t] + red[t + COUT];
        return;
    }
    // --- channel sum s ---
    int pb = blockIdx.x - KK * KK;       // 0..575
    int g  = t & 15;                     // lane within 16-lane pixel group
#pragma unroll
    for (int it = 0; it < 16; ++it) {
        int pixel = pb * 256 + it * 16 + (t >> 4);
        f32x4 v = __builtin_nontemporal_load(
            (const f32x4*)(in + (size_t)pixel * CIN) + g);
        float acc = (v.x + v.y) + (v.z + v.w);
        acc += __shfl_xor(acc, 1);
        acc += __shfl_xor(acc, 2);
        acc += __shfl_xor(acc, 4);
        acc += __shfl_xor(acc, 8);
        if (g == 0) s[pixel] = acc;
    }
}

// out[(tap,b,i), j, o] = s[b, i+x-1, j+y-1] * wsum[tap, o]
// One block per (tap,b,i): writes a contiguous 96*128 float strip (48 KB)
// with PLAIN float4 stores (A/B vs R3's non-temporal: same path as the
// 6.29 TB/s harness fills).
__global__ __launch_bounds__(256) void k_main(const float* __restrict__ s,
                                              const float* __restrict__ wsum,
                                              float* __restrict__ out) {
    int bid = blockIdx.x;                  // (tap*BQ + b)*HH + i
    int tap = bid / (BQ * HH);
    int rem = bid - tap * (BQ * HH);
    int b   = rem / HH;
    int i   = rem - b * HH;
    int x   = tap / 3, y = tap - x * 3;

    int t  = threadIdx.x;
    int ob = (t & 31) * 4;                 // output-channel base for this thread's float4
    int jt = t >> 5;                       // j sub-index 0..7

    f32x4 w = *(const f32x4*)(wsum + tap * COUT + ob);

    int ii = i + x - 1;
    bool rowok = (unsigned)ii < (unsigned)HH;
    const float* srow = s + ((size_t)b * HH + (rowok ? ii : 0)) * WWD;
    float* orow = out + (size_t)bid * (WWD * COUT) + ob;

#pragma unroll
    for (int it = 0; it < WWD / 8; ++it) {
        int j  = it * 8 + jt;
        int jj = j + y - 1;
        float sv = (rowok && (unsigned)jj < (unsigned)WWD) ? srow[jj] : 0.f;
        f32x4 v = { sv * w.x, sv * w.y, sv * w.z, sv * w.w };
        *(f32x4*)(orow + (size_t)j * COUT) = v;
    }
}

extern "C" void kernel_launch(void* const* d_in, const int* in_sizes, int n_in,
                              void* d_out, int out_size, void* d_ws, size_t ws_size,
                              hipStream_t stream) {
    const float* in = (const float*)d_in[0];   // [16,96,96,64]
    const float* W  = (const float*)d_in[1];   // [3,3,128,128]
    float* out  = (float*)d_out;               // [3,3,16,96,96,128]
    float* s    = (float*)d_ws;                              // 147456 floats
    float* wsum = (float*)d_ws + NPIX;                       // 1152 floats

    k_prep<<<KK * KK + NPIX / 256, 256, 0, stream>>>(in, W, s, wsum);
    k_main<<<KK * KK * BQ * HH, 256, 0, stream>>>(s, wsum, out);
}